// Round 3
// baseline (485.029 us; speedup 1.0000x reference)
//
#include <hip/hip_runtime.h>
#include <hip/hip_cooperative_groups.h>
#include <math.h>

namespace cg = cooperative_groups;

// Problem: y (8,3,256,256) f32, atoms (256,3,8,8) f32. ATOM=8 STRIDE=4 ->
// Hp=Wp=63, NPATCH=8*63*63=31752, D=192, K=256 atoms, 25 ISTA iterations.
// ISTA in G-form: c_{t+1} = shrink(G c_t + q/L), G = I - X/L.
// R2 lesson: node gaps + DVFS-cold single-block head cost ~100us -> fuse the
// WHOLE pipeline into ONE cooperative kernel (512 blocks x 512 thr, exactly
// co-resident at 2 blocks/CU). Block 0 runs the L-chain in the overlap
// window while everyone extracts patches; G is finalized per-block in regs.
#define NPATCH 31752
#define TILE   64          // patches per block = 2 streams x 32
#define PSTR   200         // p_lds row stride in f16 (400 B)
#define MSTR   200         // lchain LDS row stride in f16

typedef _Float16 f16;
typedef __attribute__((ext_vector_type(2))) _Float16 f16x2;
typedef __attribute__((ext_vector_type(4))) _Float16 f16x4;
typedef __attribute__((ext_vector_type(8))) _Float16 f16x8;
typedef __attribute__((ext_vector_type(2))) __fp16   hf16x2;   // cvt_pkrtz return type
typedef __attribute__((ext_vector_type(4))) float    f32x4;
#define MFMA16 __builtin_amdgcn_mfma_f32_16x16x32_f16

union HU { f16x2 h; hf16x2 g; unsigned u; };

__device__ __forceinline__ f16x2 pk2(float a, float b)
{
    HU r; r.g = __builtin_amdgcn_cvt_pkrtz(a, b);
    return r.h;
}

// soft-threshold on a packed f16 pair: sign(v) * max(|v| - thr, 0)
__device__ __forceinline__ f16x2 shrink2(f16x2 v, f16x2 thr2)
{
    HU a; a.h = v;
    unsigned sgn = a.u & 0x80008000u;
    a.u &= 0x7FFF7FFFu;
    f16x2 t = a.h - thr2;
    t = __builtin_elementwise_max(t, (f16x2)(f16)0);
    HU r; r.h = t; r.u |= sgn;
    return r.h;
}

// ===========================================================================
// FUSED cooperative kernel: 512 blocks x 512 threads, 2 blocks/CU resident.
__global__ __launch_bounds__(512, 4)
void fused_kernel(const float* __restrict__ atoms, const float* __restrict__ y,
                  float* __restrict__ As, f16* __restrict__ Ap,
                  f16* __restrict__ Ab, f16* __restrict__ Xp,
                  float* __restrict__ scal, float* __restrict__ out, int out_n)
{
    __shared__ __align__(16) unsigned char smem[76800];
    __shared__ float red[8];
    __shared__ float trc[16];
    __shared__ float part[16];

    f16*      p_lds    = (f16*)smem;              // 25600 B
    f16*      c_lds    = (f16*)(smem + 25600);    // 32768 B
    float*    mean_lds = (float*)(smem + 58368);  // 256 B
    unsigned* pco      = (unsigned*)(smem + 58624);
    f16*      mM       = (f16*)smem;              // block 0: 192 x MSTR = 76800 B

    const int tid = threadIdx.x, bid = blockIdx.x;
    const int wv = tid >> 6, lane = tid & 63, quad = lane >> 4, l16 = lane & 15;
    const int base = bid * TILE;
    cg::grid_group grid = cg::this_grid();

    // ---- S0a: zero out (all blocks, grid-stride float4)
    {
        float4* o4 = (float4*)out;
        int tot4 = out_n >> 2;
        for (int u = bid * 512 + tid; u < tot4; u += 512 * 512)
            o4[u] = (float4){0.f, 0.f, 0.f, 0.f};
    }
    // ---- S0b: normalize + pack (blocks 0..255, row b = bid; 192 live thr)
    float nv = 0.0f;
    if (bid < 256) {
        if (tid < 192) nv = atoms[bid * 192 + tid];
        float s = nv * nv, r = nv;
        #pragma unroll
        for (int m = 1; m < 64; m <<= 1) {
            s += __shfl_xor(s, m, 64);
            r += __shfl_xor(r, m, 64);
        }
        if (lane == 0) { part[wv] = s; part[8 + wv] = r; }
    }
    __syncthreads();
    if (bid < 256 && tid < 192) {
        float s = part[0] + part[1] + part[2];
        float r = part[8] + part[9] + part[10];
        float rn = 1.0f / sqrtf(s);
        float a  = nv * rn;
        if (tid == 0) As[bid] = r * rn;
        f16 ah = (f16)a;
        {   // Ap: A-operand frags, row-tile I over atoms, K=192 (6 ks)
            int I = bid >> 4, l16b = bid & 15;
            int ks = tid >> 5, q = (tid >> 3) & 3, j = tid & 7;
            Ap[((I*6 + ks)*64 + q*16 + l16b)*8 + j] = ah;
        }
        {   // Ab: frags with d as row dim, K=256 atoms (8 ks)
            int dt = tid >> 4, dl = tid & 15;
            int ks = bid >> 5, q = (bid >> 3) & 3, j = bid & 7;
            Ab[((dt*8 + ks)*64 + q*16 + dl)*8 + j] = ah;
        }
    }
    __threadfence();
    grid.sync();

    // ---- S1: overlap window --------------------------------------------
    if (bid == 0) {
        // L-chain, single-LDS-buffer variant (src reads -> regs, barrier,
        // writeback). M = A^T A then 8 trace-normalized squarings.
        const int g3 = (wv >> 1) * 3;
        const int h6 = (wv & 1) * 6;
        const f16x8* AbV = (const f16x8*)Ab;
        f32x4 acc[3][6];
        #pragma unroll
        for (int it = 0; it < 3; ++it)
            #pragma unroll
            for (int jj = 0; jj < 6; ++jj) acc[it][jj] = (f32x4){0,0,0,0};
        for (int ks = 0; ks < 8; ++ks) {
            f16x8 bf[6];
            #pragma unroll
            for (int jj = 0; jj < 6; ++jj) bf[jj] = AbV[((h6 + jj)*8 + ks)*64 + lane];
            #pragma unroll
            for (int it = 0; it < 3; ++it) {
                f16x8 af = AbV[((g3 + it)*8 + ks)*64 + lane];
                #pragma unroll
                for (int jj = 0; jj < 6; ++jj)
                    acc[it][jj] = MFMA16(af, bf[jj], acc[it][jj], 0, 0, 0);
            }
        }
        #pragma unroll
        for (int it = 0; it < 3; ++it) {
            int I = g3 + it;
            #pragma unroll
            for (int jj = 0; jj < 6; ++jj) {
                int J = h6 + jj;
                f16x2 lo = pk2(acc[it][jj][0], acc[it][jj][1]);
                f16x2 hi = pk2(acc[it][jj][2], acc[it][jj][3]);
                f16x4 cc; cc[0]=lo[0]; cc[1]=lo[1]; cc[2]=hi[0]; cc[3]=hi[1];
                *(f16x4*)&mM[(J*16 + l16)*MSTR + I*16 + quad*4] = cc;
            }
        }
        __syncthreads();

        float rprev = 1.0f;
        for (int t = 1; t <= 8; ++t) {
            const float inv = 1.0f / rprev;
            const float inv2 = inv * inv;
            f32x4 a2[3][6];
            #pragma unroll
            for (int it = 0; it < 3; ++it)
                #pragma unroll
                for (int jj = 0; jj < 6; ++jj) a2[it][jj] = (f32x4){0,0,0,0};
            for (int ksd = 0; ksd < 6; ++ksd) {
                f16x8 bf[6];
                #pragma unroll
                for (int jj = 0; jj < 6; ++jj)
                    bf[jj] = *(const f16x8*)&mM[((h6 + jj)*16 + l16)*MSTR + ksd*32 + quad*8];
                #pragma unroll
                for (int it = 0; it < 3; ++it) {
                    f16x8 af = *(const f16x8*)&mM[((g3 + it)*16 + l16)*MSTR + ksd*32 + quad*8];
                    #pragma unroll
                    for (int jj = 0; jj < 6; ++jj)
                        a2[it][jj] = MFMA16(af, bf[jj], a2[it][jj], 0, 0, 0);
                }
            }
            __syncthreads();               // all reads of mM done
            float dsum = 0.0f;
            #pragma unroll
            for (int it = 0; it < 3; ++it) {
                int I = g3 + it;
                #pragma unroll
                for (int jj = 0; jj < 6; ++jj) {
                    int J = h6 + jj;
                    float v0 = a2[it][jj][0] * inv2;
                    float v1 = a2[it][jj][1] * inv2;
                    float v2 = a2[it][jj][2] * inv2;
                    float v3 = a2[it][jj][3] * inv2;
                    f16x2 lo = pk2(v0, v1);
                    f16x2 hi = pk2(v2, v3);
                    f16x4 cc; cc[0]=lo[0]; cc[1]=lo[1]; cc[2]=hi[0]; cc[3]=hi[1];
                    *(f16x4*)&mM[(J*16 + l16)*MSTR + I*16 + quad*4] = cc;
                    if (J == I) {
                        int dg = l16 - quad*4;
                        if (dg >= 0 && dg < 4)
                            dsum += (dg == 0 ? v0 : dg == 1 ? v1 : dg == 2 ? v2 : v3);
                    }
                }
            }
            #pragma unroll
            for (int m = 1; m < 64; m <<= 1) dsum += __shfl_xor(dsum, m, 64);
            if (lane == 0) red[wv] = dsum;
            __syncthreads();               // writes + red visible
            float r = red[0] + red[1] + red[2] + red[3]
                    + red[4] + red[5] + red[6] + red[7];
            if (tid == 0) trc[t] = r;
            rprev = r;
            __syncthreads();               // red consumed before next rewrite
        }
        if (tid == 0) {
            float a = 0.0f;
            #pragma unroll
            for (int u = 1; u <= 8; ++u) a += exp2f(-(float)u) * log2f(trc[u]);
            float L = exp2f(a);
            scal[16] = 1.0f / L;
            scal[17] = 0.1f / L;
        }
        __syncthreads();                   // mM dead; smem reusable
    } else if (bid <= 16) {
        // Xp strip: I-tile (bid-1). X = A A^T via Ap frags (both operands).
        // Store TRANSPOSED (X symmetric) so g is contiguous -> f16x4 store.
        const int I = bid - 1;
        const f16x8* ApV = (const f16x8*)Ap;
        #pragma unroll
        for (int jj = 0; jj < 2; ++jj) {
            int J = wv*2 + jj;
            f32x4 acc = (f32x4){0,0,0,0};
            #pragma unroll
            for (int ks = 0; ks < 6; ++ks) {
                f16x8 af = ApV[(I*6 + ks)*64 + lane];
                f16x8 bf = ApV[(J*6 + ks)*64 + lane];
                acc = MFMA16(af, bf, acc, 0, 0, 0);
            }
            f16x2 lo = pk2(acc[0], acc[1]);
            f16x2 hi = pk2(acc[2], acc[3]);
            f16x4 cc; cc[0]=lo[0]; cc[1]=lo[1]; cc[2]=hi[0]; cc[3]=hi[1];
            int ks2 = I >> 1;
            int q2  = (2*I + (quad >> 1)) & 3;
            int j2  = (quad & 1) * 4;
            *(f16x4*)&Xp[(((J*8 + ks2)*64) + q2*16 + l16)*8 + j2] = cc;
        }
    }
    // ---- extraction (ALL blocks; block 0 after its chain)
    {
        int n_l = tid >> 3, qq = tid & 7;
        int n = base + n_l; if (n >= NPATCH) n = NPATCH - 1;
        int b = n / 3969, rem = n - b * 3969;
        int r = rem / 63, sc = rem - r * 63;
        float s = 0.0f;
        #pragma unroll
        for (int u = 0; u < 3; ++u) {
            int d  = qq * 24 + u * 8;
            int ch = d >> 6, id = (d & 63) >> 3;
            const float* src = &y[((b*3 + ch)*256 + (r*4 + id))*256 + sc*4];
            float4 a = *(const float4*)src;
            float4 bq = *(const float4*)(src + 4);
            s += a.x + a.y + a.z + a.w + bq.x + bq.y + bq.z + bq.w;
            f16x8 h = { (f16)a.x, (f16)a.y, (f16)a.z, (f16)a.w,
                        (f16)bq.x, (f16)bq.y, (f16)bq.z, (f16)bq.w };
            *(f16x8*)&p_lds[n_l * PSTR + d] = h;
        }
        s += __shfl_xor(s, 1, 64);
        s += __shfl_xor(s, 2, 64);
        s += __shfl_xor(s, 4, 64);
        if (qq == 0) {
            mean_lds[n_l] = s * (1.0f / 192.0f);
            pco[n_l] = ((unsigned)b << 16) | ((unsigned)r << 8) | (unsigned)sc;
        }
    }
    __threadfence();
    grid.sync();

    // ---- S2: everything below is the R2 mega body -----------------------
    const float invL = scal[16];
    const float thr  = scal[17];
    const f16x2 thr2 = { (f16)thr, (f16)thr };

    #define CWADDR(st, rt, ct) \
        ((st)*8192 + ((ct)*8 + wv)*512 \
         + (((rt)*2 + (quad>>1))*16 + l16)*8 + (quad&1)*4)
    #define LDB0(st, ks) (*(const f16x8*)&c_lds[(st)*8192 + (ks)*512 + lane*8])
    #define LDB1(st, ks) (*(const f16x8*)&c_lds[(st)*8192 + (8 + (ks))*512 + lane*8])

    // G-slice finalize in regs: greg = I - invL * X  (from Xp frags)
    f16x8 greg[2][8];
    {
        const f16x8* XpV = (const f16x8*)Xp;
        #pragma unroll
        for (int rt = 0; rt < 2; ++rt) {
            int r = (wv*2 + rt)*16 + l16;
            #pragma unroll
            for (int ks = 0; ks < 8; ++ks) {
                f16x8 xv = XpV[((wv*2 + rt)*8 + ks)*64 + lane];
                float f[8];
                #pragma unroll
                for (int j = 0; j < 8; ++j) {
                    int c = ks*32 + quad*8 + j;
                    float d = (r == c) ? 1.0f : 0.0f;
                    f[j] = fmaf(-invL, (float)xv[j], d);
                }
                f16x2 p0 = pk2(f[0], f[1]), p1 = pk2(f[2], f[3]);
                f16x2 p2 = pk2(f[4], f[5]), p3 = pk2(f[6], f[7]);
                f16x8 gg;
                gg[0]=p0[0]; gg[1]=p0[1]; gg[2]=p1[0]; gg[3]=p1[1];
                gg[4]=p2[0]; gg[5]=p2[1]; gg[6]=p3[0]; gg[7]=p3[1];
                greg[rt][ks] = gg;
            }
        }
    }

    // ---- phase 1: q = A p^T per stream; qs packed f16; c1 = shrink(qs)
    f16x2 qslo[2][2][2], qshi[2][2][2];
    const f16x8* ApV = (const f16x8*)Ap;
    #pragma unroll
    for (int st = 0; st < 2; ++st) {
        f32x4 qf[2][2];
        #pragma unroll
        for (int rt = 0; rt < 2; ++rt)
            #pragma unroll
            for (int ct = 0; ct < 2; ++ct) qf[rt][ct] = (f32x4){0,0,0,0};
        #pragma unroll
        for (int ks = 0; ks < 6; ++ks) {
            f16x8 bf[2];
            #pragma unroll
            for (int ct = 0; ct < 2; ++ct)
                bf[ct] = *(const f16x8*)&p_lds[(st*32 + ct*16 + l16)*PSTR + ks*32 + quad*8];
            #pragma unroll
            for (int rt = 0; rt < 2; ++rt) {
                f16x8 af = ApV[((wv*2 + rt)*6 + ks)*64 + lane];
                #pragma unroll
                for (int ct = 0; ct < 2; ++ct)
                    qf[rt][ct] = MFMA16(af, bf[ct], qf[rt][ct], 0, 0, 0);
            }
        }
        #pragma unroll
        for (int rt = 0; rt < 2; ++rt) {
            float4 av = *(const float4*)&As[(wv*2 + rt)*16 + quad*4];
            #pragma unroll
            for (int ct = 0; ct < 2; ++ct) {
                float mn = mean_lds[st*32 + ct*16 + l16];
                float q0 = (qf[rt][ct][0] - mn*av.x) * invL;
                float q1 = (qf[rt][ct][1] - mn*av.y) * invL;
                float q2 = (qf[rt][ct][2] - mn*av.z) * invL;
                float q3 = (qf[rt][ct][3] - mn*av.w) * invL;
                f16x2 lo = pk2(q0, q1);
                f16x2 hi = pk2(q2, q3);
                qslo[st][rt][ct] = lo;  qshi[st][rt][ct] = hi;
                f16x2 clo = shrink2(lo, thr2);
                f16x2 chi = shrink2(hi, thr2);
                f16x4 cc; cc[0]=clo[0]; cc[1]=clo[1]; cc[2]=chi[0]; cc[3]=chi[1];
                *(f16x4*)&c_lds[CWADDR(st, rt, ct)] = cc;
            }
        }
    }
    __syncthreads();

    // ---- phase 2: 24 iterations, dual-stream pipelined with cross-barrier
    // B-fragment prefetch (pa/pb hold ks=0,1 of the stream about to compute).
    f16x8 pa0 = LDB0(0,0), pa1 = LDB1(0,0), pa2 = LDB0(0,1), pa3 = LDB1(0,1);
    for (int it = 0; it < 24; ++it) {
        f32x4 af[2][2];
        #pragma unroll
        for (int rt = 0; rt < 2; ++rt)
            #pragma unroll
            for (int ct = 0; ct < 2; ++ct) af[rt][ct] = (f32x4){0,0,0,0};
        __builtin_amdgcn_s_setprio(1);
        #pragma unroll
        for (int ks = 0; ks < 8; ++ks) {
            f16x8 b0 = (ks == 0) ? pa0 : (ks == 1) ? pa2 : LDB0(0, ks);
            f16x8 b1 = (ks == 0) ? pa1 : (ks == 1) ? pa3 : LDB1(0, ks);
            #pragma unroll
            for (int rt = 0; rt < 2; ++rt) {
                af[rt][0] = MFMA16(greg[rt][ks], b0, af[rt][0], 0, 0, 0);
                af[rt][1] = MFMA16(greg[rt][ks], b1, af[rt][1], 0, 0, 0);
            }
        }
        __builtin_amdgcn_s_setprio(0);
        __syncthreads();
        f16x8 pb0 = LDB0(1,0), pb1 = LDB1(1,0), pb2 = LDB0(1,1), pb3 = LDB1(1,1);
        #pragma unroll
        for (int rt = 0; rt < 2; ++rt)
            #pragma unroll
            for (int ct = 0; ct < 2; ++ct) {
                f16x2 vlo = pk2(af[rt][ct][0], af[rt][ct][1]) + qslo[0][rt][ct];
                f16x2 vhi = pk2(af[rt][ct][2], af[rt][ct][3]) + qshi[0][rt][ct];
                vlo = shrink2(vlo, thr2);
                vhi = shrink2(vhi, thr2);
                f16x4 cc; cc[0]=vlo[0]; cc[1]=vlo[1]; cc[2]=vhi[0]; cc[3]=vhi[1];
                *(f16x4*)&c_lds[CWADDR(0, rt, ct)] = cc;
            }
        #pragma unroll
        for (int rt = 0; rt < 2; ++rt)
            #pragma unroll
            for (int ct = 0; ct < 2; ++ct) af[rt][ct] = (f32x4){0,0,0,0};
        __builtin_amdgcn_s_setprio(1);
        #pragma unroll
        for (int ks = 0; ks < 8; ++ks) {
            f16x8 b0 = (ks == 0) ? pb0 : (ks == 1) ? pb2 : LDB0(1, ks);
            f16x8 b1 = (ks == 0) ? pb1 : (ks == 1) ? pb3 : LDB1(1, ks);
            #pragma unroll
            for (int rt = 0; rt < 2; ++rt) {
                af[rt][0] = MFMA16(greg[rt][ks], b0, af[rt][0], 0, 0, 0);
                af[rt][1] = MFMA16(greg[rt][ks], b1, af[rt][1], 0, 0, 0);
            }
        }
        __builtin_amdgcn_s_setprio(0);
        __syncthreads();
        pa0 = LDB0(0,0); pa1 = LDB1(0,0); pa2 = LDB0(0,1); pa3 = LDB1(0,1);
        #pragma unroll
        for (int rt = 0; rt < 2; ++rt)
            #pragma unroll
            for (int ct = 0; ct < 2; ++ct) {
                f16x2 vlo = pk2(af[rt][ct][0], af[rt][ct][1]) + qslo[1][rt][ct];
                f16x2 vhi = pk2(af[rt][ct][2], af[rt][ct][3]) + qshi[1][rt][ct];
                vlo = shrink2(vlo, thr2);
                vhi = shrink2(vhi, thr2);
                f16x4 cc; cc[0]=vlo[0]; cc[1]=vlo[1]; cc[2]=vhi[0]; cc[3]=vhi[1];
                *(f16x4*)&c_lds[CWADDR(1, rt, ct)] = cc;
            }
    }
    __syncthreads();

    // ---- phase 3: rec = c^T A + mean, /count folded, scatter-add into out
    const int nt = wv >> 2, dtb = 3 * (wv & 3);
    const f16x8* AbV = (const f16x8*)Ab;
    #pragma unroll
    for (int st = 0; st < 2; ++st) {
        f32x4 rf[3];
        #pragma unroll
        for (int u = 0; u < 3; ++u) rf[u] = (f32x4){0,0,0,0};
        #pragma unroll
        for (int ks = 0; ks < 8; ++ks) {
            f16x8 afr = *(const f16x8*)&c_lds[st*8192 + (nt*8 + ks)*512 + lane*8];
            #pragma unroll
            for (int u = 0; u < 3; ++u) {
                f16x8 bb = AbV[((dtb + u)*8 + ks)*64 + lane];
                rf[u] = MFMA16(afr, bb, rf[u], 0, 0, 0);
            }
        }
        #pragma unroll
        for (int g = 0; g < 4; ++g) {
            int nl = nt*16 + quad*4 + g;
            int n  = base + st*32 + nl;
            if (n < NPATCH) {
                unsigned pc = pco[st*32 + nl];
                int b = pc >> 16, r = (pc >> 8) & 255, sc = pc & 255;
                float mn = mean_lds[st*32 + nl];
                #pragma unroll
                for (int u = 0; u < 3; ++u) {
                    int d  = (dtb + u)*16 + l16;
                    int ch = d >> 6, dh = (d & 63) >> 3, dw = d & 7;
                    int h  = r*4 + dh, w2 = sc*4 + dw;
                    int cnth = min(62, h >> 2)  - (max(h - 4, 0) >> 2) + 1;
                    int cntw = min(62, w2 >> 2) - (max(w2 - 4, 0) >> 2) + 1;
                    float rcp = 1.0f / (float)(cnth * cntw);
                    atomicAdd(&out[((b*3 + ch)*256 + (r*4 + dh))*256 + sc*4 + dw],
                              (rf[u][g] + mn) * rcp);
                }
            }
        }
    }
    #undef CWADDR
    #undef LDB0
    #undef LDB1
}

// ===========================================================================
// FALLBACK path (R2 3-kernel pipeline) if cooperative launch is unavailable.
__global__ __launch_bounds__(512, 1)
void lchain_kernel(const float* __restrict__ atoms,
                   float* __restrict__ A, float* __restrict__ As,
                   f16* __restrict__ Ap, f16* __restrict__ Ab,
                   float* __restrict__ scal)
{
    __shared__ __align__(16) f16 mls[2 * 192 * MSTR];
    __shared__ float red[8];
    __shared__ float trc[16];
    const int tid = threadIdx.x, wv = tid >> 6, lane = tid & 63;
    const int quad = lane >> 4, l16 = lane & 15;
    {
        float* ldsf = (float*)mls;
        for (int c = 0; c < 2; ++c) {
            const float4* src4 = (const float4*)(atoms + c * 128 * 192);
            float4* dst4 = (float4*)ldsf;
            #pragma unroll
            for (int k = 0; k < 12; ++k)
                dst4[tid + k * 512] = src4[tid + k * 512];
            __syncthreads();
            #pragma unroll 4
            for (int rr = 0; rr < 16; ++rr) {
                int lr = wv * 16 + rr;
                int b  = c * 128 + lr;
                float v0 = ldsf[lr * 192 + lane];
                float v1 = ldsf[lr * 192 +  64 + lane];
                float v2 = ldsf[lr * 192 + 128 + lane];
                float s = v0 * v0 + v1 * v1 + v2 * v2;
                float r = v0 + v1 + v2;
                #pragma unroll
                for (int m = 1; m < 64; m <<= 1) {
                    s += __shfl_xor(s, m, 64);
                    r += __shfl_xor(r, m, 64);
                }
                float rn = 1.0f / sqrtf(s);
                if (lane == 0) As[b] = r * rn;
                const int I = b >> 4, l16b = b & 15;
                const int ksb = b >> 5, qb = (b >> 3) & 3, jb = b & 7;
                float vv[3] = { v0, v1, v2 };
                #pragma unroll
                for (int u = 0; u < 3; ++u) {
                    int t = u * 64 + lane;
                    float a = vv[u] * rn;
                    A[b * 192 + t] = a;
                    f16 ah = (f16)a;
                    int ks = t >> 5, q = (t >> 3) & 3, j = t & 7;
                    Ap[((I * 6 + ks) * 64 + q * 16 + l16b) * 8 + j] = ah;
                    int dt = t >> 4, dl = t & 15;
                    Ab[((dt * 8 + ksb) * 64 + qb * 16 + dl) * 8 + jb] = ah;
                }
            }
            __syncthreads();
        }
    }
    __threadfence_block();
    const int g3 = (wv >> 1) * 3;
    const int h6 = (wv & 1) * 6;
    const f16x8* AbV = (const f16x8*)Ab;
    f32x4 acc[3][6];
    #pragma unroll
    for (int it = 0; it < 3; ++it)
        #pragma unroll
        for (int jj = 0; jj < 6; ++jj) acc[it][jj] = (f32x4){0,0,0,0};
    for (int ks = 0; ks < 8; ++ks) {
        f16x8 bf[6];
        #pragma unroll
        for (int jj = 0; jj < 6; ++jj) bf[jj] = AbV[((h6 + jj)*8 + ks)*64 + lane];
        #pragma unroll
        for (int it = 0; it < 3; ++it) {
            f16x8 af = AbV[((g3 + it)*8 + ks)*64 + lane];
            #pragma unroll
            for (int jj = 0; jj < 6; ++jj)
                acc[it][jj] = MFMA16(af, bf[jj], acc[it][jj], 0, 0, 0);
        }
    }
    #pragma unroll
    for (int it = 0; it < 3; ++it) {
        int I = g3 + it;
        #pragma unroll
        for (int jj = 0; jj < 6; ++jj) {
            int J = h6 + jj;
            f16x2 lo = pk2(acc[it][jj][0], acc[it][jj][1]);
            f16x2 hi = pk2(acc[it][jj][2], acc[it][jj][3]);
            f16x4 cc; cc[0]=lo[0]; cc[1]=lo[1]; cc[2]=hi[0]; cc[3]=hi[1];
            *(f16x4*)&mls[(J*16 + l16)*MSTR + I*16 + quad*4] = cc;
        }
    }
    __syncthreads();
    float rprev = 1.0f;
    for (int t = 1; t <= 8; ++t) {
        const f16* src = mls + ((t & 1) ^ 1) * (192 * MSTR);
        f16*       dst = mls + (t & 1) * (192 * MSTR);
        const float inv = 1.0f / rprev;
        const float inv2 = inv * inv;
        f32x4 a2[3][6];
        #pragma unroll
        for (int it = 0; it < 3; ++it)
            #pragma unroll
            for (int jj = 0; jj < 6; ++jj) a2[it][jj] = (f32x4){0,0,0,0};
        for (int ksd = 0; ksd < 6; ++ksd) {
            f16x8 bf[6];
            #pragma unroll
            for (int jj = 0; jj < 6; ++jj)
                bf[jj] = *(const f16x8*)&src[((h6 + jj)*16 + l16)*MSTR + ksd*32 + quad*8];
            #pragma unroll
            for (int it = 0; it < 3; ++it) {
                f16x8 af = *(const f16x8*)&src[((g3 + it)*16 + l16)*MSTR + ksd*32 + quad*8];
                #pragma unroll
                for (int jj = 0; jj < 6; ++jj)
                    a2[it][jj] = MFMA16(af, bf[jj], a2[it][jj], 0, 0, 0);
            }
        }
        float dsum = 0.0f;
        #pragma unroll
        for (int it = 0; it < 3; ++it) {
            int I = g3 + it;
            #pragma unroll
            for (int jj = 0; jj < 6; ++jj) {
                int J = h6 + jj;
                float v0 = a2[it][jj][0] * inv2;
                float v1 = a2[it][jj][1] * inv2;
                float v2 = a2[it][jj][2] * inv2;
                float v3 = a2[it][jj][3] * inv2;
                f16x2 lo = pk2(v0, v1);
                f16x2 hi = pk2(v2, v3);
                f16x4 cc; cc[0]=lo[0]; cc[1]=lo[1]; cc[2]=hi[0]; cc[3]=hi[1];
                *(f16x4*)&dst[(J*16 + l16)*MSTR + I*16 + quad*4] = cc;
                if (J == I) {
                    int dg = l16 - quad*4;
                    if (dg >= 0 && dg < 4)
                        dsum += (dg == 0 ? v0 : dg == 1 ? v1 : dg == 2 ? v2 : v3);
                }
            }
        }
        #pragma unroll
        for (int m = 1; m < 64; m <<= 1) dsum += __shfl_xor(dsum, m, 64);
        if (lane == 0) red[wv] = dsum;
        __syncthreads();
        float r = red[0] + red[1] + red[2] + red[3]
                + red[4] + red[5] + red[6] + red[7];
        if (tid == 0) trc[t] = r;
        rprev = r;
        __syncthreads();
    }
    if (tid == 0) {
        float a = 0.0f;
        #pragma unroll
        for (int u = 1; u <= 8; ++u) a += exp2f(-(float)u) * log2f(trc[u]);
        float L = exp2f(a);
        scal[16] = 1.0f / L;
        scal[17] = 0.1f / L;
    }
}

__global__ void gpack_kernel(const float* __restrict__ A, const float* __restrict__ scal,
                             f16* __restrict__ Gp, float* __restrict__ out, int out_n)
{
    __shared__ float arow[192];
    __shared__ float xrow[256];
    {
        float4* o4 = (float4*)out;
        int idx = blockIdx.x * blockDim.x + threadIdx.x;
        int tot4 = out_n >> 2;
        for (int u = idx; u < tot4; u += gridDim.x * blockDim.x)
            o4[u] = (float4){0.f, 0.f, 0.f, 0.f};
    }
    int i = blockIdx.x, j = threadIdx.x;
    const float invL = scal[16];
    if (j < 192) arow[j] = A[i*192 + j];
    __syncthreads();
    float s = 0.0f;
    #pragma unroll 4
    for (int d = 0; d < 192; d += 4) {
        float4 av = *(const float4*)&A[j*192 + d];
        s += arow[d]*av.x + arow[d+1]*av.y + arow[d+2]*av.z + arow[d+3]*av.w;
    }
    xrow[j] = (i == j ? 1.0f : 0.0f) - s * invL;
    __syncthreads();
    if (j < 32) {
        int ks = j >> 2, q = j & 3;
        f16x8 h;
        #pragma unroll
        for (int u = 0; u < 8; ++u) h[u] = (f16)xrow[ks*32 + q*8 + u];
        int I = i >> 4, lane = q*16 + (i & 15);
        *(f16x8*)&Gp[(((I*8 + ks)*64) + lane)*8] = h;
    }
}

__global__ __launch_bounds__(512, 4)
void mega_kernel(const float* __restrict__ y,
                 const f16* __restrict__ Gp, const f16* __restrict__ Ap,
                 const f16* __restrict__ Ab, const float* __restrict__ As,
                 const float* __restrict__ scal, float* __restrict__ out)
{
    __shared__ f16      p_lds[TILE * PSTR];
    __shared__ f16      c_lds[2 * 16 * 512];
    __shared__ float    mean_lds[TILE];
    __shared__ unsigned pco[TILE];

    const int tid  = threadIdx.x;
    const int base = blockIdx.x * TILE;
    const int wv = tid >> 6, lane = tid & 63, quad = lane >> 4, l16 = lane & 15;
    const float invL = scal[16];
    const float thr  = scal[17];
    const f16x2 thr2 = { (f16)thr, (f16)thr };

    #define CWADDR(st, rt, ct) \
        ((st)*8192 + ((ct)*8 + wv)*512 \
         + (((rt)*2 + (quad>>1))*16 + l16)*8 + (quad&1)*4)
    #define LDB0(st, ks) (*(const f16x8*)&c_lds[(st)*8192 + (ks)*512 + lane*8])
    #define LDB1(st, ks) (*(const f16x8*)&c_lds[(st)*8192 + (8 + (ks))*512 + lane*8])

    f16x8 greg[2][8];
    {
        const f16x8* GpV = (const f16x8*)Gp;
        #pragma unroll
        for (int rt = 0; rt < 2; ++rt)
            #pragma unroll
            for (int ks = 0; ks < 8; ++ks)
                greg[rt][ks] = GpV[((wv*2 + rt)*8 + ks)*64 + lane];
    }
    {
        int n_l = tid >> 3, qq = tid & 7;
        int n = base + n_l; if (n >= NPATCH) n = NPATCH - 1;
        int b = n / 3969, rem = n - b * 3969;
        int r = rem / 63, sc = rem - r * 63;
        float s = 0.0f;
        #pragma unroll
        for (int u = 0; u < 3; ++u) {
            int d  = qq * 24 + u * 8;
            int ch = d >> 6, id = (d & 63) >> 3;
            const float* src = &y[((b*3 + ch)*256 + (r*4 + id))*256 + sc*4];
            float4 a = *(const float4*)src;
            float4 bq = *(const float4*)(src + 4);
            s += a.x + a.y + a.z + a.w + bq.x + bq.y + bq.z + bq.w;
            f16x8 h = { (f16)a.x, (f16)a.y, (f16)a.z, (f16)a.w,
                        (f16)bq.x, (f16)bq.y, (f16)bq.z, (f16)bq.w };
            *(f16x8*)&p_lds[n_l * PSTR + d] = h;
        }
        s += __shfl_xor(s, 1, 64);
        s += __shfl_xor(s, 2, 64);
        s += __shfl_xor(s, 4, 64);
        if (qq == 0) {
            mean_lds[n_l] = s * (1.0f / 192.0f);
            pco[n_l] = ((unsigned)b << 16) | ((unsigned)r << 8) | (unsigned)sc;
        }
    }
    __syncthreads();

    f16x2 qslo[2][2][2], qshi[2][2][2];
    const f16x8* ApV = (const f16x8*)Ap;
    #pragma unroll
    for (int st = 0; st < 2; ++st) {
        f32x4 qf[2][2];
        #pragma unroll
        for (int rt = 0; rt < 2; ++rt)
            #pragma unroll
            for (int ct = 0; ct < 2; ++ct) qf[rt][ct] = (f32x4){0,0,0,0};
        #pragma unroll
        for (int ks = 0; ks < 6; ++ks) {
            f16x8 bf[2];
            #pragma unroll
            for (int ct = 0; ct < 2; ++ct)
                bf[ct] = *(const f16x8*)&p_lds[(st*32 + ct*16 + l16)*PSTR + ks*32 + quad*8];
            #pragma unroll
            for (int rt = 0; rt < 2; ++rt) {
                f16x8 af = ApV[((wv*2 + rt)*6 + ks)*64 + lane];
                #pragma unroll
                for (int ct = 0; ct < 2; ++ct)
                    qf[rt][ct] = MFMA16(af, bf[ct], qf[rt][ct], 0, 0, 0);
            }
        }
        #pragma unroll
        for (int rt = 0; rt < 2; ++rt) {
            float4 av = *(const float4*)&As[(wv*2 + rt)*16 + quad*4];
            #pragma unroll
            for (int ct = 0; ct < 2; ++ct) {
                float mn = mean_lds[st*32 + ct*16 + l16];
                float q0 = (qf[rt][ct][0] - mn*av.x) * invL;
                float q1 = (qf[rt][ct][1] - mn*av.y) * invL;
                float q2 = (qf[rt][ct][2] - mn*av.z) * invL;
                float q3 = (qf[rt][ct][3] - mn*av.w) * invL;
                f16x2 lo = pk2(q0, q1);
                f16x2 hi = pk2(q2, q3);
                qslo[st][rt][ct] = lo;  qshi[st][rt][ct] = hi;
                f16x2 clo = shrink2(lo, thr2);
                f16x2 chi = shrink2(hi, thr2);
                f16x4 cc; cc[0]=clo[0]; cc[1]=clo[1]; cc[2]=chi[0]; cc[3]=chi[1];
                *(f16x4*)&c_lds[CWADDR(st, rt, ct)] = cc;
            }
        }
    }
    __syncthreads();

    f16x8 pa0 = LDB0(0,0), pa1 = LDB1(0,0), pa2 = LDB0(0,1), pa3 = LDB1(0,1);
    for (int it = 0; it < 24; ++it) {
        f32x4 af[2][2];
        #pragma unroll
        for (int rt = 0; rt < 2; ++rt)
            #pragma unroll
            for (int ct = 0; ct < 2; ++ct) af[rt][ct] = (f32x4){0,0,0,0};
        __builtin_amdgcn_s_setprio(1);
        #pragma unroll
        for (int ks = 0; ks < 8; ++ks) {
            f16x8 b0 = (ks == 0) ? pa0 : (ks == 1) ? pa2 : LDB0(0, ks);
            f16x8 b1 = (ks == 0) ? pa1 : (ks == 1) ? pa3 : LDB1(0, ks);
            #pragma unroll
            for (int rt = 0; rt < 2; ++rt) {
                af[rt][0] = MFMA16(greg[rt][ks], b0, af[rt][0], 0, 0, 0);
                af[rt][1] = MFMA16(greg[rt][ks], b1, af[rt][1], 0, 0, 0);
            }
        }
        __builtin_amdgcn_s_setprio(0);
        __syncthreads();
        f16x8 pb0 = LDB0(1,0), pb1 = LDB1(1,0), pb2 = LDB0(1,1), pb3 = LDB1(1,1);
        #pragma unroll
        for (int rt = 0; rt < 2; ++rt)
            #pragma unroll
            for (int ct = 0; ct < 2; ++ct) {
                f16x2 vlo = pk2(af[rt][ct][0], af[rt][ct][1]) + qslo[0][rt][ct];
                f16x2 vhi = pk2(af[rt][ct][2], af[rt][ct][3]) + qshi[0][rt][ct];
                vlo = shrink2(vlo, thr2);
                vhi = shrink2(vhi, thr2);
                f16x4 cc; cc[0]=vlo[0]; cc[1]=vlo[1]; cc[2]=vhi[0]; cc[3]=vhi[1];
                *(f16x4*)&c_lds[CWADDR(0, rt, ct)] = cc;
            }
        #pragma unroll
        for (int rt = 0; rt < 2; ++rt)
            #pragma unroll
            for (int ct = 0; ct < 2; ++ct) af[rt][ct] = (f32x4){0,0,0,0};
        __builtin_amdgcn_s_setprio(1);
        #pragma unroll
        for (int ks = 0; ks < 8; ++ks) {
            f16x8 b0 = (ks == 0) ? pb0 : (ks == 1) ? pb2 : LDB0(1, ks);
            f16x8 b1 = (ks == 0) ? pb1 : (ks == 1) ? pb3 : LDB1(1, ks);
            #pragma unroll
            for (int rt = 0; rt < 2; ++rt) {
                af[rt][0] = MFMA16(greg[rt][ks], b0, af[rt][0], 0, 0, 0);
                af[rt][1] = MFMA16(greg[rt][ks], b1, af[rt][1], 0, 0, 0);
            }
        }
        __builtin_amdgcn_s_setprio(0);
        __syncthreads();
        pa0 = LDB0(0,0); pa1 = LDB1(0,0); pa2 = LDB0(0,1); pa3 = LDB1(0,1);
        #pragma unroll
        for (int rt = 0; rt < 2; ++rt)
            #pragma unroll
            for (int ct = 0; ct < 2; ++ct) {
                f16x2 vlo = pk2(af[rt][ct][0], af[rt][ct][1]) + qslo[1][rt][ct];
                f16x2 vhi = pk2(af[rt][ct][2], af[rt][ct][3]) + qshi[1][rt][ct];
                vlo = shrink2(vlo, thr2);
                vhi = shrink2(vhi, thr2);
                f16x4 cc; cc[0]=vlo[0]; cc[1]=vlo[1]; cc[2]=vhi[0]; cc[3]=vhi[1];
                *(f16x4*)&c_lds[CWADDR(1, rt, ct)] = cc;
            }
    }
    __syncthreads();

    const int nt = wv >> 2, dtb = 3 * (wv & 3);
    const f16x8* AbV = (const f16x8*)Ab;
    #pragma unroll
    for (int st = 0; st < 2; ++st) {
        f32x4 rf[3];
        #pragma unroll
        for (int u = 0; u < 3; ++u) rf[u] = (f32x4){0,0,0,0};
        #pragma unroll
        for (int ks = 0; ks < 8; ++ks) {
            f16x8 afr = *(const f16x8*)&c_lds[st*8192 + (nt*8 + ks)*512 + lane*8];
            #pragma unroll
            for (int u = 0; u < 3; ++u) {
                f16x8 bb = AbV[((dtb + u)*8 + ks)*64 + lane];
                rf[u] = MFMA16(afr, bb, rf[u], 0, 0, 0);
            }
        }
        #pragma unroll
        for (int g = 0; g < 4; ++g) {
            int nl = nt*16 + quad*4 + g;
            int n  = base + st*32 + nl;
            if (n < NPATCH) {
                unsigned pc = pco[st*32 + nl];
                int b = pc >> 16, r = (pc >> 8) & 255, sc = pc & 255;
                float mn = mean_lds[st*32 + nl];
                #pragma unroll
                for (int u = 0; u < 3; ++u) {
                    int d  = (dtb + u)*16 + l16;
                    int ch = d >> 6, dh = (d & 63) >> 3, dw = d & 7;
                    int h  = r*4 + dh, w2 = sc*4 + dw;
                    int cnth = min(62, h >> 2)  - (max(h - 4, 0) >> 2) + 1;
                    int cntw = min(62, w2 >> 2) - (max(w2 - 4, 0) >> 2) + 1;
                    float rcp = 1.0f / (float)(cnth * cntw);
                    atomicAdd(&out[((b*3 + ch)*256 + (r*4 + dh))*256 + sc*4 + dw],
                              (rf[u][g] + mn) * rcp);
                }
            }
        }
    }
    #undef CWADDR
    #undef LDB0
    #undef LDB1
}

// ---------------------------------------------------------------------------
extern "C" void kernel_launch(void* const* d_in, const int* in_sizes, int n_in,
                              void* d_out, int out_size, void* d_ws, size_t ws_size,
                              hipStream_t stream)
{
    const float* y     = (const float*)d_in[0];
    const float* atoms = (const float*)d_in[1];
    float* out = (float*)d_out;
    float* ws  = (float*)d_ws;

    // ws layout (float offsets); shared between fused and fallback paths
    float* A    = ws;                       // 49152 floats (fallback only)
    float* As   = ws + 49152;               // 256
    float* scal = ws + 49408;               // 32
    f16*   Ap   = (f16*)(ws + 49440);       // 49152 f16
    f16*   Ab   = (f16*)(ws + 74016);       // 49152 f16
    f16*   Xp   = (f16*)(ws + 98592);       // 65536 f16 (fallback: Gp)
    int    outn = out_size;

    void* kargs[] = { (void*)&atoms, (void*)&y, (void*)&As, (void*)&Ap,
                      (void*)&Ab, (void*)&Xp, (void*)&scal, (void*)&out,
                      (void*)&outn };
    hipError_t e = hipLaunchCooperativeKernel((const void*)fused_kernel,
                                              dim3(512), dim3(512),
                                              kargs, 0, stream);
    if (e != hipSuccess) {
        // fallback: 3-node pipeline (R2)
        lchain_kernel<<<1, 512, 0, stream>>>(atoms, A, As, Ap, Ab, scal);
        gpack_kernel <<<256, 256, 0, stream>>>(A, scal, Xp, out, outn);
        mega_kernel  <<<(NPATCH + TILE - 1) / TILE, 512, 0, stream>>>
            (y, Xp, Ap, Ab, As, scal, out);
    }
}

// Round 4
// 195.096 us; speedup vs baseline: 2.4861x; 2.4861x over previous
//
#include <hip/hip_runtime.h>
#include <math.h>

// Problem: y (8,3,256,256) f32, atoms (256,3,8,8) f32. ATOM=8 STRIDE=4 ->
// Hp=Wp=63, NPATCH=8*63*63=31752, D=192, K=256 atoms, 25 ISTA iterations.
// ISTA in G-form: c_{t+1} = shrink(G c_t + q/L), G = I - X/L.
// Cost model (R0-R3 measured): node gap ~15us, single-block chain ~20us,
// scattered scalar stores from ONE block ~55us (R1/R2 mistake), cooperative
// grid.sync ~ 100+us (R3 mistake). -> 3 nodes, all packing done by 256-block
// kernels, Xp strips run as extra blocks of the lchain node (no dependency
// on invL), G finalized per-block in regs inside mega (gpack eliminated).
#define NPATCH 31752
#define TILE   64          // patches per block = 2 streams x 32
#define PSTR   200         // p_lds row stride in f16 (400 B)
#define MSTR   200         // lchain LDS row stride in f16

typedef _Float16 f16;
typedef __attribute__((ext_vector_type(2))) _Float16 f16x2;
typedef __attribute__((ext_vector_type(4))) _Float16 f16x4;
typedef __attribute__((ext_vector_type(8))) _Float16 f16x8;
typedef __attribute__((ext_vector_type(2))) __fp16   hf16x2;   // cvt_pkrtz return type
typedef __attribute__((ext_vector_type(4))) float    f32x4;
#define MFMA16 __builtin_amdgcn_mfma_f32_16x16x32_f16

union HU { f16x2 h; hf16x2 g; unsigned u; };

__device__ __forceinline__ f16x2 pk2(float a, float b)
{
    HU r; r.g = __builtin_amdgcn_cvt_pkrtz(a, b);
    return r.h;
}

// soft-threshold on a packed f16 pair: sign(v) * max(|v| - thr, 0)
__device__ __forceinline__ f16x2 shrink2(f16x2 v, f16x2 thr2)
{
    HU a; a.h = v;
    unsigned sgn = a.u & 0x80008000u;
    a.u &= 0x7FFF7FFFu;
    f16x2 t = a.h - thr2;
    t = __builtin_elementwise_max(t, (f16x2)(f16)0);
    HU r; r.h = t; r.u |= sgn;
    return r.h;
}

// ---------------------------------------------------------------------------
// K1: fused normalize + pack (R0's proven 256-block form) + out zeroing.
// Block b = atom row b (192 threads = 3 waves).
__global__ void fusedpack_kernel(const float* __restrict__ atoms,
                                 float* __restrict__ As,
                                 f16* __restrict__ Ap, f16* __restrict__ Ab,
                                 float* __restrict__ out, int out_n)
{
    __shared__ float part[6];
    const int b = blockIdx.x, t = threadIdx.x;    // 192 threads
    // zero out (grid-stride float4; 393216 f4 / 49152 thr = 8 each)
    {
        float4* o4 = (float4*)out;
        int tot4 = out_n >> 2;
        for (int u = b * 192 + t; u < tot4; u += 256 * 192)
            o4[u] = (float4){0.f, 0.f, 0.f, 0.f};
    }
    float v = atoms[b*192 + t];
    float s = v*v, r = v;
    #pragma unroll
    for (int m = 1; m < 64; m <<= 1) { s += __shfl_xor(s, m, 64); r += __shfl_xor(r, m, 64); }
    const int wv = t >> 6, lane = t & 63;
    if (lane == 0) { part[wv] = s; part[3 + wv] = r; }
    __syncthreads();
    s = part[0] + part[1] + part[2];
    r = part[3] + part[4] + part[5];
    float rn = 1.0f / sqrtf(s);
    float a  = v * rn;
    if (t == 0) As[b] = r * rn;
    f16 ah = (f16)a;
    // Ap: (row=b, col=t) A-operand frags, 16-row tiles over atoms, K=192
    {
        int I = b >> 4, l16 = b & 15;
        int ks = t >> 5, q = (t >> 3) & 3, j = t & 7;
        Ap[(((I*6 + ks)*64) + q*16 + l16)*8 + j] = ah;
    }
    // Ab: (k=b, d=t) frags with d as row dim, K=256 atoms
    {
        int dt = t >> 4, dl = t & 15;
        int ks = b >> 5, q = (b >> 3) & 3, j = b & 7;
        Ab[(((dt*8 + ks)*64) + q*16 + dl)*8 + j] = ah;
    }
    (void)lane;
}

// ---------------------------------------------------------------------------
// K2: 17 blocks. Block 0: L-chain (single-block, LDS ping-pong, M = A^T A
// then 8 trace-normalized squarings; L = prod r_u^(2^-u)). Blocks 1..16:
// Xp strips — X = A A^T tiles in A-operand fragment layout via the
// symmetric transposed store (validated in R3). Strips need no invL.
__global__ __launch_bounds__(512, 1)
void lchain_kernel(const f16* __restrict__ Ab, const f16* __restrict__ Ap,
                   f16* __restrict__ Xp, float* __restrict__ scal)
{
    __shared__ __align__(16) f16 mls[2 * 192 * MSTR];      // 153600 B
    __shared__ float red[8];
    __shared__ float trc[16];
    const int tid = threadIdx.x, bid = blockIdx.x;
    const int wv = tid >> 6, lane = tid & 63;
    const int quad = lane >> 4, l16 = lane & 15;

    if (bid > 0) {
        // ---- Xp strip: I-tile (bid-1), store transposed (X symmetric)
        const int I = bid - 1;
        const f16x8* ApV = (const f16x8*)Ap;
        #pragma unroll
        for (int jj = 0; jj < 2; ++jj) {
            int J = wv*2 + jj;
            f32x4 acc = (f32x4){0,0,0,0};
            #pragma unroll
            for (int ks = 0; ks < 6; ++ks) {
                f16x8 af = ApV[(I*6 + ks)*64 + lane];
                f16x8 bf = ApV[(J*6 + ks)*64 + lane];
                acc = MFMA16(af, bf, acc, 0, 0, 0);
            }
            f16x2 lo = pk2(acc[0], acc[1]);
            f16x2 hi = pk2(acc[2], acc[3]);
            f16x4 cc; cc[0]=lo[0]; cc[1]=lo[1]; cc[2]=hi[0]; cc[3]=hi[1];
            int ks2 = I >> 1;
            int q2  = (2*I + (quad >> 1)) & 3;
            int j2  = (quad & 1) * 4;
            *(f16x4*)&Xp[(((J*8 + ks2)*64) + q2*16 + l16)*8 + j2] = cc;
        }
        return;
    }

    // ---- block 0: the chain
    const int g3 = (wv >> 1) * 3;              // I-tile base (3 tiles)
    const int h6 = (wv & 1) * 6;               // J-tile base (6 tiles)
    const f16x8* AbV = (const f16x8*)Ab;

    // phase A: M = A^T A -> mls[0] (transposed packed write)
    f32x4 acc[3][6];
    #pragma unroll
    for (int it = 0; it < 3; ++it)
        #pragma unroll
        for (int jj = 0; jj < 6; ++jj) acc[it][jj] = (f32x4){0,0,0,0};
    for (int ks = 0; ks < 8; ++ks) {
        f16x8 bf[6];
        #pragma unroll
        for (int jj = 0; jj < 6; ++jj) bf[jj] = AbV[((h6 + jj)*8 + ks)*64 + lane];
        #pragma unroll
        for (int it = 0; it < 3; ++it) {
            f16x8 af = AbV[((g3 + it)*8 + ks)*64 + lane];
            #pragma unroll
            for (int jj = 0; jj < 6; ++jj)
                acc[it][jj] = MFMA16(af, bf[jj], acc[it][jj], 0, 0, 0);
        }
    }
    #pragma unroll
    for (int it = 0; it < 3; ++it) {
        int I = g3 + it;
        #pragma unroll
        for (int jj = 0; jj < 6; ++jj) {
            int J = h6 + jj;
            f16x2 lo = pk2(acc[it][jj][0], acc[it][jj][1]);
            f16x2 hi = pk2(acc[it][jj][2], acc[it][jj][3]);
            f16x4 cc; cc[0]=lo[0]; cc[1]=lo[1]; cc[2]=hi[0]; cc[3]=hi[1];
            *(f16x4*)&mls[(J*16 + l16)*MSTR + I*16 + quad*4] = cc;
        }
    }
    __syncthreads();

    float rprev = 1.0f;
    for (int t = 1; t <= 8; ++t) {
        const f16* src = mls + ((t & 1) ^ 1) * (192 * MSTR);
        f16*       dst = mls + (t & 1) * (192 * MSTR);
        const float inv = 1.0f / rprev;
        const float inv2 = inv * inv;

        f32x4 a2[3][6];
        #pragma unroll
        for (int it = 0; it < 3; ++it)
            #pragma unroll
            for (int jj = 0; jj < 6; ++jj) a2[it][jj] = (f32x4){0,0,0,0};
        for (int ksd = 0; ksd < 6; ++ksd) {
            f16x8 bf[6];
            #pragma unroll
            for (int jj = 0; jj < 6; ++jj)
                bf[jj] = *(const f16x8*)&src[((h6 + jj)*16 + l16)*MSTR + ksd*32 + quad*8];
            #pragma unroll
            for (int it = 0; it < 3; ++it) {
                f16x8 af = *(const f16x8*)&src[((g3 + it)*16 + l16)*MSTR + ksd*32 + quad*8];
                #pragma unroll
                for (int jj = 0; jj < 6; ++jj)
                    a2[it][jj] = MFMA16(af, bf[jj], a2[it][jj], 0, 0, 0);
            }
        }
        float dsum = 0.0f;
        #pragma unroll
        for (int it = 0; it < 3; ++it) {
            int I = g3 + it;
            #pragma unroll
            for (int jj = 0; jj < 6; ++jj) {
                int J = h6 + jj;
                float v0 = a2[it][jj][0] * inv2;
                float v1 = a2[it][jj][1] * inv2;
                float v2 = a2[it][jj][2] * inv2;
                float v3 = a2[it][jj][3] * inv2;
                f16x2 lo = pk2(v0, v1);
                f16x2 hi = pk2(v2, v3);
                f16x4 cc; cc[0]=lo[0]; cc[1]=lo[1]; cc[2]=hi[0]; cc[3]=hi[1];
                *(f16x4*)&dst[(J*16 + l16)*MSTR + I*16 + quad*4] = cc;
                if (J == I) {
                    int dg = l16 - quad*4;        // diagonal when l16 == quad*4+g
                    if (dg >= 0 && dg < 4)
                        dsum += (dg == 0 ? v0 : dg == 1 ? v1 : dg == 2 ? v2 : v3);
                }
            }
        }
        #pragma unroll
        for (int m = 1; m < 64; m <<= 1) dsum += __shfl_xor(dsum, m, 64);
        if (lane == 0) red[wv] = dsum;
        __syncthreads();
        float r = red[0] + red[1] + red[2] + red[3]
                + red[4] + red[5] + red[6] + red[7];
        if (tid == 0) trc[t] = r;
        rprev = r;
        __syncthreads();           // protect red[] before next step rewrites it
    }
    if (tid == 0) {
        float a = 0.0f;
        #pragma unroll
        for (int u = 1; u <= 8; ++u) a += exp2f(-(float)u) * log2f(trc[u]);
        float L = exp2f(a);
        scal[16] = 1.0f / L;
        scal[17] = 0.1f / L;       // LMBDA / L
    }
}

// ---------------------------------------------------------------------------
// K3: mega kernel. 512 threads / 8 waves; TILE=64 = 2 streams x 32 patches.
// greg finalized in regs from Xp (G = I - invL*X, element-wise — validated
// R3). Phase-2 ping-pong with cross-barrier B-fragment prefetch.
__global__ __launch_bounds__(512, 4)
void mega_kernel(const float* __restrict__ y,
                 const f16* __restrict__ Xp, const f16* __restrict__ Ap,
                 const f16* __restrict__ Ab, const float* __restrict__ As,
                 const float* __restrict__ scal, float* __restrict__ out)
{
    __shared__ f16      p_lds[TILE * PSTR];    // 25600 B
    __shared__ f16      c_lds[2 * 16 * 512];   // 32768 B: [st][ct*8+ks][lane*8+j]
    __shared__ float    mean_lds[TILE];
    __shared__ unsigned pco[TILE];             // total LDS 58880 B -> 2 blocks/CU

    const int tid  = threadIdx.x;
    const int base = blockIdx.x * TILE;
    const int wv = tid >> 6, lane = tid & 63, quad = lane >> 4, l16 = lane & 15;
    const float invL = scal[16];
    const float thr  = scal[17];
    const f16x2 thr2 = { (f16)thr, (f16)thr };

    // row-tile of c written by (wv,rt) is R = wv*2+rt -> ks-slot = wv
    #define CWADDR(st, rt, ct) \
        ((st)*8192 + ((ct)*8 + wv)*512 \
         + (((rt)*2 + (quad>>1))*16 + l16)*8 + (quad&1)*4)
    #define LDB0(st, ks) (*(const f16x8*)&c_lds[(st)*8192 + (ks)*512 + lane*8])
    #define LDB1(st, ks) (*(const f16x8*)&c_lds[(st)*8192 + (8 + (ks))*512 + lane*8])

    // ---- greg = I - invL * X  (from Xp frags, element-wise)
    f16x8 greg[2][8];
    {
        const f16x8* XpV = (const f16x8*)Xp;
        #pragma unroll
        for (int rt = 0; rt < 2; ++rt) {
            int r = (wv*2 + rt)*16 + l16;
            #pragma unroll
            for (int ks = 0; ks < 8; ++ks) {
                f16x8 xv = XpV[((wv*2 + rt)*8 + ks)*64 + lane];
                float f[8];
                #pragma unroll
                for (int j = 0; j < 8; ++j) {
                    int c = ks*32 + quad*8 + j;
                    float d = (r == c) ? 1.0f : 0.0f;
                    f[j] = fmaf(-invL, (float)xv[j], d);
                }
                f16x2 p0 = pk2(f[0], f[1]), p1 = pk2(f[2], f[3]);
                f16x2 p2 = pk2(f[4], f[5]), p3 = pk2(f[6], f[7]);
                f16x8 gg;
                gg[0]=p0[0]; gg[1]=p0[1]; gg[2]=p1[0]; gg[3]=p1[1];
                gg[4]=p2[0]; gg[5]=p2[1]; gg[6]=p3[0]; gg[7]=p3[1];
                greg[rt][ks] = gg;
            }
        }
    }

    // ---- phase 0: extraction, single pass (8 threads/patch, 24 f32 each)
    {
        int n_l = tid >> 3, qq = tid & 7;
        int n = base + n_l; if (n >= NPATCH) n = NPATCH - 1;
        int b = n / 3969, rem = n - b * 3969;
        int r = rem / 63, sc = rem - r * 63;
        float s = 0.0f;
        #pragma unroll
        for (int u = 0; u < 3; ++u) {
            int d  = qq * 24 + u * 8;
            int ch = d >> 6, id = (d & 63) >> 3;
            const float* src = &y[((b*3 + ch)*256 + (r*4 + id))*256 + sc*4];
            float4 a = *(const float4*)src;
            float4 bq = *(const float4*)(src + 4);
            s += a.x + a.y + a.z + a.w + bq.x + bq.y + bq.z + bq.w;
            f16x8 h = { (f16)a.x, (f16)a.y, (f16)a.z, (f16)a.w,
                        (f16)bq.x, (f16)bq.y, (f16)bq.z, (f16)bq.w };
            *(f16x8*)&p_lds[n_l * PSTR + d] = h;
        }
        // 8-lane group reduce (lanes n_l*8..+7 are contiguous in the wave)
        s += __shfl_xor(s, 1, 64);
        s += __shfl_xor(s, 2, 64);
        s += __shfl_xor(s, 4, 64);
        if (qq == 0) {
            mean_lds[n_l] = s * (1.0f / 192.0f);
            pco[n_l] = ((unsigned)b << 16) | ((unsigned)r << 8) | (unsigned)sc;
        }
    }
    __syncthreads();

    // ---- phase 1: q = A p^T per stream; qs packed f16; c1 = shrink(qs)
    f16x2 qslo[2][2][2], qshi[2][2][2];
    const f16x8* ApV = (const f16x8*)Ap;
    #pragma unroll
    for (int st = 0; st < 2; ++st) {
        f32x4 qf[2][2];
        #pragma unroll
        for (int rt = 0; rt < 2; ++rt)
            #pragma unroll
            for (int ct = 0; ct < 2; ++ct) qf[rt][ct] = (f32x4){0,0,0,0};
        #pragma unroll
        for (int ks = 0; ks < 6; ++ks) {
            f16x8 bf[2];
            #pragma unroll
            for (int ct = 0; ct < 2; ++ct)
                bf[ct] = *(const f16x8*)&p_lds[(st*32 + ct*16 + l16)*PSTR + ks*32 + quad*8];
            #pragma unroll
            for (int rt = 0; rt < 2; ++rt) {
                f16x8 af = ApV[((wv*2 + rt)*6 + ks)*64 + lane];
                #pragma unroll
                for (int ct = 0; ct < 2; ++ct)
                    qf[rt][ct] = MFMA16(af, bf[ct], qf[rt][ct], 0, 0, 0);
            }
        }
        #pragma unroll
        for (int rt = 0; rt < 2; ++rt) {
            float4 av = *(const float4*)&As[(wv*2 + rt)*16 + quad*4];
            #pragma unroll
            for (int ct = 0; ct < 2; ++ct) {
                float mn = mean_lds[st*32 + ct*16 + l16];
                float q0 = (qf[rt][ct][0] - mn*av.x) * invL;
                float q1 = (qf[rt][ct][1] - mn*av.y) * invL;
                float q2 = (qf[rt][ct][2] - mn*av.z) * invL;
                float q3 = (qf[rt][ct][3] - mn*av.w) * invL;
                f16x2 lo = pk2(q0, q1);
                f16x2 hi = pk2(q2, q3);
                qslo[st][rt][ct] = lo;  qshi[st][rt][ct] = hi;
                f16x2 clo = shrink2(lo, thr2);
                f16x2 chi = shrink2(hi, thr2);
                f16x4 cc; cc[0]=clo[0]; cc[1]=clo[1]; cc[2]=chi[0]; cc[3]=chi[1];
                *(f16x4*)&c_lds[CWADDR(st, rt, ct)] = cc;
            }
        }
    }
    __syncthreads();

    // ---- phase 2: 24 iterations, dual-stream pipelined with cross-barrier
    // B-fragment prefetch (pa/pb hold ks=0,1 of the stream about to compute).
    f16x8 pa0 = LDB0(0,0), pa1 = LDB1(0,0), pa2 = LDB0(0,1), pa3 = LDB1(0,1);
    for (int it = 0; it < 24; ++it) {
        f32x4 af[2][2];
        #pragma unroll
        for (int rt = 0; rt < 2; ++rt)
            #pragma unroll
            for (int ct = 0; ct < 2; ++ct) af[rt][ct] = (f32x4){0,0,0,0};
        __builtin_amdgcn_s_setprio(1);
        #pragma unroll
        for (int ks = 0; ks < 8; ++ks) {
            f16x8 b0 = (ks == 0) ? pa0 : (ks == 1) ? pa2 : LDB0(0, ks);
            f16x8 b1 = (ks == 0) ? pa1 : (ks == 1) ? pa3 : LDB1(0, ks);
            #pragma unroll
            for (int rt = 0; rt < 2; ++rt) {
                af[rt][0] = MFMA16(greg[rt][ks], b0, af[rt][0], 0, 0, 0);
                af[rt][1] = MFMA16(greg[rt][ks], b1, af[rt][1], 0, 0, 0);
            }
        }
        __builtin_amdgcn_s_setprio(0);
        __syncthreads();                       // all waves done reading cA
        // prefetch stream-B ks=0,1 (written last iter, synced above)
        f16x8 pb0 = LDB0(1,0), pb1 = LDB1(1,0), pb2 = LDB0(1,1), pb3 = LDB1(1,1);
        #pragma unroll
        for (int rt = 0; rt < 2; ++rt)
            #pragma unroll
            for (int ct = 0; ct < 2; ++ct) {
                f16x2 vlo = pk2(af[rt][ct][0], af[rt][ct][1]) + qslo[0][rt][ct];
                f16x2 vhi = pk2(af[rt][ct][2], af[rt][ct][3]) + qshi[0][rt][ct];
                vlo = shrink2(vlo, thr2);
                vhi = shrink2(vhi, thr2);
                f16x4 cc; cc[0]=vlo[0]; cc[1]=vlo[1]; cc[2]=vhi[0]; cc[3]=vhi[1];
                *(f16x4*)&c_lds[CWADDR(0, rt, ct)] = cc;
            }
        #pragma unroll
        for (int rt = 0; rt < 2; ++rt)
            #pragma unroll
            for (int ct = 0; ct < 2; ++ct) af[rt][ct] = (f32x4){0,0,0,0};
        __builtin_amdgcn_s_setprio(1);
        #pragma unroll
        for (int ks = 0; ks < 8; ++ks) {
            f16x8 b0 = (ks == 0) ? pb0 : (ks == 1) ? pb2 : LDB0(1, ks);
            f16x8 b1 = (ks == 0) ? pb1 : (ks == 1) ? pb3 : LDB1(1, ks);
            #pragma unroll
            for (int rt = 0; rt < 2; ++rt) {
                af[rt][0] = MFMA16(greg[rt][ks], b0, af[rt][0], 0, 0, 0);
                af[rt][1] = MFMA16(greg[rt][ks], b1, af[rt][1], 0, 0, 0);
            }
        }
        __builtin_amdgcn_s_setprio(0);
        __syncthreads();                       // all waves done reading cB
        // prefetch stream-A ks=0,1 for next iter (written above, synced)
        pa0 = LDB0(0,0); pa1 = LDB1(0,0); pa2 = LDB0(0,1); pa3 = LDB1(0,1);
        #pragma unroll
        for (int rt = 0; rt < 2; ++rt)
            #pragma unroll
            for (int ct = 0; ct < 2; ++ct) {
                f16x2 vlo = pk2(af[rt][ct][0], af[rt][ct][1]) + qslo[1][rt][ct];
                f16x2 vhi = pk2(af[rt][ct][2], af[rt][ct][3]) + qshi[1][rt][ct];
                vlo = shrink2(vlo, thr2);
                vhi = shrink2(vhi, thr2);
                f16x4 cc; cc[0]=vlo[0]; cc[1]=vlo[1]; cc[2]=vhi[0]; cc[3]=vhi[1];
                *(f16x4*)&c_lds[CWADDR(1, rt, ct)] = cc;
            }
    }
    __syncthreads();

    // ---- phase 3: rec = c^T A + mean, /count folded, scatter-add into out
    const int nt = wv >> 2, dtb = 3 * (wv & 3);
    const f16x8* AbV = (const f16x8*)Ab;
    #pragma unroll
    for (int st = 0; st < 2; ++st) {
        f32x4 rf[3];
        #pragma unroll
        for (int u = 0; u < 3; ++u) rf[u] = (f32x4){0,0,0,0};
        #pragma unroll
        for (int ks = 0; ks < 8; ++ks) {
            f16x8 afr = *(const f16x8*)&c_lds[st*8192 + (nt*8 + ks)*512 + lane*8];
            #pragma unroll
            for (int u = 0; u < 3; ++u) {
                f16x8 bb = AbV[((dtb + u)*8 + ks)*64 + lane];
                rf[u] = MFMA16(afr, bb, rf[u], 0, 0, 0);
            }
        }
        #pragma unroll
        for (int g = 0; g < 4; ++g) {
            int nl = nt*16 + quad*4 + g;
            int n  = base + st*32 + nl;
            if (n < NPATCH) {
                unsigned pc = pco[st*32 + nl];
                int b = pc >> 16, r = (pc >> 8) & 255, sc = pc & 255;
                float mn = mean_lds[st*32 + nl];
                #pragma unroll
                for (int u = 0; u < 3; ++u) {
                    int d  = (dtb + u)*16 + l16;
                    int ch = d >> 6, dh = (d & 63) >> 3, dw = d & 7;
                    int h  = r*4 + dh, w2 = sc*4 + dw;
                    int cnth = min(62, h >> 2)  - (max(h - 4, 0) >> 2) + 1;
                    int cntw = min(62, w2 >> 2) - (max(w2 - 4, 0) >> 2) + 1;
                    float rcp = 1.0f / (float)(cnth * cntw);
                    atomicAdd(&out[((b*3 + ch)*256 + (r*4 + dh))*256 + sc*4 + dw],
                              (rf[u][g] + mn) * rcp);
                }
            }
        }
    }
    #undef CWADDR
    #undef LDB0
    #undef LDB1
}

// ---------------------------------------------------------------------------
extern "C" void kernel_launch(void* const* d_in, const int* in_sizes, int n_in,
                              void* d_out, int out_size, void* d_ws, size_t ws_size,
                              hipStream_t stream)
{
    const float* y     = (const float*)d_in[0];
    const float* atoms = (const float*)d_in[1];
    float* out = (float*)d_out;
    float* ws  = (float*)d_ws;

    // ws layout (float offsets); all f16 regions 16B-aligned
    float* As   = ws + 49152;               // 256
    float* scal = ws + 49408;               // 32
    f16*   Ap   = (f16*)(ws + 49440);       // 49152 f16
    f16*   Ab   = (f16*)(ws + 74016);       // 49152 f16
    f16*   Xp   = (f16*)(ws + 98592);       // 65536 f16
    int    outn = out_size;

    fusedpack_kernel<<<256, 192, 0, stream>>>(atoms, As, Ap, Ab, out, outn);
    lchain_kernel   <<<17, 512,  0, stream>>>(Ab, Ap, Xp, scal);
    mega_kernel     <<<(NPATCH + TILE - 1) / TILE, 512, 0, stream>>>
        (y, Xp, Ap, Ab, As, scal, out);
}